// Round 4
// baseline (61887.170 us; speedup 1.0000x reference)
//
#include <hip/hip_runtime.h>
#include <hip/hip_cooperative_groups.h>
#include <math.h>

namespace cg = cooperative_groups;

#define V    50257
#define E    512
#define H    1024
#define S    128
#define BS   8
#define T    64
#define SOS  1
#define EOS  2
#define NEGV (-1e9f)
#define H3   (3*H)
#define KS   16
#define RPK  ((E+H)/KS)   // 96
#define TKCH 6283         // 8*6283 = 50264 >= V
#define CB   197          // gemv col-blocks: 197*256 = 50432 >= V
#define SMB  21504        // shared-union bytes (max = topk phase)

struct Params {
    const float *emb, *Wx, *Wh, *Wout, *bout, *enc, *h0;
    float *out;
    float *h, *hcT, *part, *lpart, *attg, *cand_v, *cm, *clp;
    int   *cand_i;
    float *cum0, *cum1;
    int *len0, *len1, *fin0, *fin1, *lat0, *lat1, *tok0, *tok1;
};

// ================= phase bodies (single source of truth, bit-exact) =================

__device__ __forceinline__ void init_body(const Params& p) {
    int t = threadIdx.x;
    for (int i = t; i < BS*H; i += 256) p.h[i] = p.h0[i % H];
    for (int i = t; i < BS*T; i += 256) p.tok0[i] = 0;
    if (t < BS) { p.cum0[t] = 0.f; p.len0[t] = 1; p.fin0[t] = 0; p.lat0[t] = SOS; }
}

__device__ __forceinline__ void gru_body(const Params& p, char* sm, int jb, int k,
                                         const int* __restrict__ lat) {
    int t = threadIdx.x;
    int j = jb*256 + t;
    int c0 = k * RPK;
    float* vals = (float*)sm;                  // RPK*8 = 3072 B
    for (int m = t; m < RPK*8; m += 256) {
        int c = c0 + (m >> 3);
        int b = m & 7;
        float v;
        if (c < E) v = p.emb[(size_t)lat[b]*E + c];
        else       v = p.h[b*H + (c - E)];
        vals[m] = v;
    }
    __syncthreads();
    float pz[BS] = {0}, pr[BS] = {0}, pnx[BS] = {0}, pnh[BS] = {0};
    for (int cc = 0; cc < RPK; ++cc) {
        int c = c0 + cc;
        bool isx = (c < E);
        const float* Wrow = isx ? (p.Wx + (size_t)c*H3) : (p.Wh + (size_t)(c-E)*H3);
        float wz = Wrow[j];
        float wr = Wrow[j + H];
        float wn = Wrow[j + 2*H];
        #pragma unroll
        for (int b = 0; b < BS; ++b) {
            float v = vals[cc*8 + b];
            pz[b] += v * wz;
            pr[b] += v * wr;
            if (isx) pnx[b] += v * wn; else pnh[b] += v * wn;
        }
    }
    #pragma unroll
    for (int b = 0; b < BS; ++b) {
        p.part[(((size_t)k*4 + 0)*8 + b)*H + j] = pz[b];
        p.part[(((size_t)k*4 + 1)*8 + b)*H + j] = pr[b];
        p.part[(((size_t)k*4 + 2)*8 + b)*H + j] = pnx[b];
        p.part[(((size_t)k*4 + 3)*8 + b)*H + j] = pnh[b];
    }
    __syncthreads();
}

// gate reduce + attention scores + softmax (ctx moved to own phase; att stored to attg)
__device__ __forceinline__ void gateA_body(const Params& p, char* sm, int b) {
    int t = threadIdx.x;
    float* hn   = (float*)sm;          // 1024 f
    float* att  = hn + H;              // 128 f
    float* smax = att + S;
    float* ssum = smax + 1;
    for (int j = t; j < H; j += 256) {
        float pz = 0.f, pr = 0.f, pnx = 0.f, pnh = 0.f;
        #pragma unroll
        for (int k = 0; k < KS; ++k) {
            pz  += p.part[(((size_t)k*4 + 0)*8 + b)*H + j];
            pr  += p.part[(((size_t)k*4 + 1)*8 + b)*H + j];
            pnx += p.part[(((size_t)k*4 + 2)*8 + b)*H + j];
            pnh += p.part[(((size_t)k*4 + 3)*8 + b)*H + j];
        }
        float z = 1.f / (1.f + expf(-pz));
        float r = 1.f / (1.f + expf(-pr));
        float n = tanhf(pnx + r * pnh);
        float v = (1.f - z) * n + z * p.h[b*H + j];
        hn[j] = v;
        p.hcT[(size_t)j*8 + b] = v;
    }
    __syncthreads();
    int wave = t >> 6, lane = t & 63;
    for (int s2 = wave; s2 < S; s2 += 4) {
        float acc = 0.f;
        #pragma unroll 4
        for (int hh = lane; hh < H; hh += 64)
            acc += hn[hh] * p.enc[(size_t)s2*H + hh];
        #pragma unroll
        for (int off = 32; off; off >>= 1) acc += __shfl_down(acc, off, 64);
        if (lane == 0) att[s2] = acc;
    }
    __syncthreads();
    if (t == 0) {
        float m = -3.0e38f;
        for (int s2 = 0; s2 < S; ++s2) m = fmaxf(m, att[s2]);
        *smax = m;
    }
    __syncthreads();
    if (t < S) att[t] = expf(att[t] - *smax);
    __syncthreads();
    if (t == 0) {
        float sum = 0.f;
        for (int s2 = 0; s2 < S; ++s2) sum += att[s2];
        *ssum = sum;
    }
    __syncthreads();
    if (t < S) { att[t] = att[t] / *ssum; p.attg[b*S + t] = att[t]; }
    __syncthreads();
}

// ctx: hcT[H+j][b] = sum_s att[s]*enc[s][j] — same ascending-s chain, 32-way parallel
__device__ __forceinline__ void ctx_body(const Params& p, char* sm, int vb) {
    int t = threadIdx.x;
    int b = vb & 7, jc = vb >> 3;      // jc 0..3
    float* att = (float*)sm;           // 128 f
    if (t < S) att[t] = p.attg[b*S + t];
    __syncthreads();
    int j = jc*256 + t;
    float acc = 0.f;
    for (int s2 = 0; s2 < S; ++s2) acc += att[s2] * p.enc[(size_t)s2*H + j];
    p.hcT[(size_t)(H + j)*8 + b] = acc;
    __syncthreads();
}

__device__ __forceinline__ void gemv_body(const Params& p, char* sm, int cb, int rs) {
    int t = threadIdx.x;
    int r0 = rs * 256;
    int c  = cb*256 + t;
    float* hc = (float*)sm;            // 2048 f
    for (int m = t; m < 256*8; m += 256) hc[m] = p.hcT[(size_t)r0*8 + m];
    __syncthreads();
    int cl = (c < V) ? c : (V - 1);
    const float* wp = p.Wout + (size_t)r0*V + cl;
    float a[8] = {0,0,0,0,0,0,0,0};
    #pragma unroll 8
    for (int rr = 0; rr < 256; ++rr) {
        float w = __builtin_nontemporal_load(wp + (size_t)rr*V);   // cache hint only
        const float* hr = hc + rr*8;
        #pragma unroll
        for (int b = 0; b < 8; ++b) a[b] += hr[b] * w;
    }
    if (c < V) {
        #pragma unroll
        for (int b = 0; b < 8; ++b)
            p.lpart[((size_t)rs*8 + b)*V + c] = a[b];
    }
    __syncthreads();
}

__device__ __forceinline__ void topk_body(const Params& p, char* sm, int b, int c) {
    int t = threadIdx.x;
    float* pm = (float*)(sm);            // 256 f
    float* pl = (float*)(sm + 1024);     // 256 f
    float* pv = (float*)(sm + 2048);     // 2048 f
    int*   pi = (int*)  (sm + 10240);    // 2048 i
    float* rv = (float*)(sm + 18432);    // 256 f
    int*   ri = (int*)  (sm + 19456);    // 256 i
    int*   rp = (int*)  (sm + 20480);    // 256 i

    int vstart = c * TKCH;
    int vend = (vstart + TKCH < V) ? (vstart + TKCH) : V;
    float bv[8]; int bi[8];
    #pragma unroll
    for (int r = 0; r < 8; ++r) { bv[r] = -3.0e38f; bi[r] = 0x7fffffff; }
    float m = -3.0e38f, l = 0.f;
    for (int v = vstart + t; v < vend; v += 256) {
        float x = p.bout[v];
        #pragma unroll
        for (int r = 0; r < 8; ++r)
            x += p.lpart[((size_t)r*8 + b)*V + v];
        if (x > m) { l = l * expf(m - x) + 1.f; m = x; }
        else         l += expf(x - m);
        if (x > bv[7]) {
            bv[7] = x; bi[7] = v;
            #pragma unroll
            for (int q = 7; q > 0; --q) {
                if (bv[q] > bv[q-1]) {
                    float tv = bv[q]; bv[q] = bv[q-1]; bv[q-1] = tv;
                    int   ti = bi[q]; bi[q] = bi[q-1]; bi[q-1] = ti;
                }
            }
        }
    }
    pm[t] = m; pl[t] = l;
    __syncthreads();
    for (int off = 128; off; off >>= 1) {
        if (t < off) {
            float m2 = pm[t+off], l2 = pl[t+off];
            float M = fmaxf(pm[t], m2);
            pl[t] = pl[t]*expf(pm[t]-M) + l2*expf(m2-M);
            pm[t] = M;
        }
        __syncthreads();
    }
    if (t == 0) { p.cm[b*8 + c] = pm[0]; p.clp[b*8 + c] = pl[0]; }

    #pragma unroll
    for (int r = 0; r < 8; ++r) { pv[t*8+r] = bv[r]; pi[t*8+r] = bi[r]; }
    __syncthreads();
    for (int round = 0; round < 8; ++round) {
        float lv = -3.0e38f; int li = 0x7fffffff, lp = -1;
        #pragma unroll
        for (int r = 0; r < 8; ++r) {
            float v2 = pv[t*8+r]; int i2 = pi[t*8+r];
            if (v2 > lv || (v2 == lv && i2 < li)) { lv = v2; li = i2; lp = t*8+r; }
        }
        rv[t] = lv; ri[t] = li; rp[t] = lp;
        __syncthreads();
        for (int off = 128; off; off >>= 1) {
            if (t < off) {
                if (rv[t+off] > rv[t] || (rv[t+off] == rv[t] && ri[t+off] < ri[t])) {
                    rv[t] = rv[t+off]; ri[t] = ri[t+off]; rp[t] = rp[t+off];
                }
            }
            __syncthreads();
        }
        if (t == 0) {
            p.cand_v[(b*8 + c)*8 + round] = rv[0];
            p.cand_i[(b*8 + c)*8 + round] = ri[0];
            pv[rp[0]] = -3.0e38f; pi[rp[0]] = 0x7fffffff;
        }
        __syncthreads();
    }
    __syncthreads();
}

__device__ __forceinline__ void merge_body(const Params& p, char* sm,
    const float* cum_i, const int* len_i, const int* fin_i,
    const int* lat_i, const int* tok_i,
    float* cum_o, int* len_o, int* fin_o, int* lat_o, int* tok_o, int step)
{
    int t = threadIdx.x;
    float* cv   = (float*)(sm);          // 512 f
    int*   ci   = (int*)  (sm + 2048);   // 512 i
    float* t8v  = (float*)(sm + 4096);   // 64 f
    int*   t8i  = (int*)  (sm + 4352);   // 64 i
    float* lse  = (float*)(sm + 4608);   // 8 f
    float* flat = (float*)(sm + 4640);   // 64 f
    float* ccum = (float*)(sm + 4896);   // 64 f
    int*   clen = (int*)  (sm + 5152);   // 64 i
    int*   sel  = (int*)  (sm + 5408);   // 8 i

    for (int i = t; i < 512; i += 256) { cv[i] = p.cand_v[i]; ci[i] = p.cand_i[i]; }
    __syncthreads();
    if (t < 8) {
        int b = t;
        float m = -3.0e38f, l = 0.f;
        for (int c = 0; c < 8; ++c) {
            float m2 = p.cm[b*8 + c], l2 = p.clp[b*8 + c];
            float M = fmaxf(m, m2);
            l = l*expf(m - M) + l2*expf(m2 - M);
            m = M;
        }
        lse[b] = m + logf(l);
        unsigned long long tk = 0ull;
        for (int round = 0; round < 8; ++round) {
            float bvv = -3.4e38f; int bii = 0x7fffffff, bp = 0;
            for (int i = 0; i < 64; ++i) {
                if ((tk >> i) & 1ull) continue;
                float v2 = cv[b*64 + i]; int i2 = ci[b*64 + i];
                if (v2 > bvv || (v2 == bvv && i2 < bii)) { bvv = v2; bii = i2; bp = i; }
            }
            tk |= 1ull << bp;
            t8v[b*8 + round] = bvv;
            t8i[b*8 + round] = bii;
        }
    }
    __syncthreads();
    if (t < 64) {
        int b = t >> 3, j = t & 7;
        int alive = fin_i[b] ? 0 : 1;
        float lp = t8v[b*8 + j] - lse[b];
        float cc = cum_i[b] + (alive ? lp : 0.f);
        int   cln = len_i[b] + alive;
        float score = cc / (float)cln;
        bool valid = (alive || j == 0) && ((step > 0) || (b == 0));
        flat[t] = valid ? score : NEGV;
        ccum[t] = cc; clen[t] = cln;
    }
    __syncthreads();
    if (t == 0) {
        unsigned long long tk = 0ull;
        for (int r = 0; r < 8; ++r) {
            float bestv = -3.4e38f; int bidx = 0;
            for (int i = 0; i < 64; ++i) {
                if (!((tk >> i) & 1ull) && flat[i] > bestv) { bestv = flat[i]; bidx = i; }
            }
            tk |= 1ull << bidx; sel[r] = bidx;
        }
    }
    __syncthreads();
    if (t < 8) {
        int idx = sel[t];
        int parent = idx >> 3, child = idx & 7;
        int p_fin = fin_i[parent];
        int new_tok = t8i[parent*8 + child];
        cum_o[t] = ccum[idx];
        len_o[t] = clen[idx];
        fin_o[t] = (p_fin || new_tok == EOS) ? 1 : 0;
        lat_o[t] = p_fin ? lat_i[parent] : new_tok;
    }
    __syncthreads();
    for (int m = t; m < BS*T; m += 256) {
        int nb2 = m / T, pos = m % T;
        int idx = sel[nb2];
        int parent = idx >> 3, child = idx & 7;
        int p_fin = fin_i[parent];
        int p_len = len_i[parent];
        int new_tok = t8i[parent*8 + child];
        int val = tok_i[parent*T + pos];
        if (pos == p_len - 1 && !p_fin) val = new_tok;
        tok_o[m] = val;
    }
    for (int m = t; m < BS*H; m += 256) {
        int nb2 = m / H, j = m % H;
        int parent = sel[nb2] >> 3;
        p.h[m] = p.hcT[(size_t)j*8 + parent];
    }
    __syncthreads();
}

__device__ __forceinline__ void final_body(const Params& p, char* sm) {
    int t = threadIdx.x;
    int* bestIdx = (int*)sm;
    if (t == 0) {
        bool anyf = false;
        for (int b = 0; b < BS; ++b) anyf = anyf || (p.fin0[b] != 0);
        float bestv = -3.4e38f; int bi_ = 0;
        for (int b = 0; b < BS; ++b) {
            float sc = p.cum0[b] / (float)p.len0[b];
            float adj = anyf ? (p.fin0[b] ? sc : NEGV) : sc;
            if (adj > bestv) { bestv = adj; bi_ = b; }
        }
        *bestIdx = bi_;
        p.out[T] = p.cum0[bi_] / (float)p.len0[bi_];
    }
    __syncthreads();
    if (t < T) p.out[t] = (float)p.tok0[*bestIdx*T + t];
}

// ================= persistent cooperative kernel =================
__global__ __launch_bounds__(256, 2) void k_all(Params p) {
    cg::grid_group grid = cg::this_grid();
    __shared__ __align__(16) char sm[SMB];
    int bid = blockIdx.x, nb = gridDim.x;

    if (bid == 0) init_body(p);
    grid.sync();

    for (int s = 0; s < T; ++s) {
        int pp = s & 1;
        const float* cum_i = pp ? p.cum1 : p.cum0;
        float*       cum_o = pp ? p.cum0 : p.cum1;
        const int* len_i = pp ? p.len1 : p.len0;  int* len_o = pp ? p.len0 : p.len1;
        const int* fin_i = pp ? p.fin1 : p.fin0;  int* fin_o = pp ? p.fin0 : p.fin1;
        const int* lat_i = pp ? p.lat1 : p.lat0;  int* lat_o = pp ? p.lat0 : p.lat1;
        const int* tok_i = pp ? p.tok1 : p.tok0;  int* tok_o = pp ? p.tok0 : p.tok1;

        for (int vb = bid; vb < 64; vb += nb)      gru_body(p, sm, vb & 3, vb >> 2, lat_i);
        grid.sync();
        for (int vb = bid; vb < 8; vb += nb)       gateA_body(p, sm, vb);
        grid.sync();
        for (int vb = bid; vb < 32; vb += nb)      ctx_body(p, sm, vb);
        grid.sync();
        for (int vb = bid; vb < CB*8; vb += nb)    gemv_body(p, sm, vb % CB, vb / CB);
        grid.sync();
        for (int vb = bid; vb < 64; vb += nb)      topk_body(p, sm, vb & 7, vb >> 3);
        grid.sync();
        if (bid == 0) merge_body(p, sm, cum_i, len_i, fin_i, lat_i, tok_i,
                                 cum_o, len_o, fin_o, lat_o, tok_o, s);
        grid.sync();
    }
    if (bid == 0) final_body(p, sm);
}

// ================= fallback: same bodies, multi-kernel (round-1 parity) =================
__global__ void k_init_s(Params p) { init_body(p); }
__global__ __launch_bounds__(256) void k_gru_s(Params p, int s) {
    __shared__ __align__(16) char sm[3072];
    const int* lat = (s & 1) ? p.lat1 : p.lat0;
    gru_body(p, sm, blockIdx.x, blockIdx.y, lat);
}
__global__ __launch_bounds__(256) void k_gate_s(Params p) {
    __shared__ __align__(16) char sm[4624];
    gateA_body(p, sm, blockIdx.x);
}
__global__ __launch_bounds__(256) void k_ctx_s(Params p) {
    __shared__ __align__(16) char sm[512];
    ctx_body(p, sm, blockIdx.x);
}
__global__ __launch_bounds__(256) void k_gemv_s(Params p) {
    __shared__ __align__(16) char sm[8192];
    gemv_body(p, sm, blockIdx.x, blockIdx.y);
}
__global__ __launch_bounds__(256) void k_topk_s(Params p) {
    __shared__ __align__(16) char sm[SMB];
    topk_body(p, sm, blockIdx.x, blockIdx.y);
}
__global__ __launch_bounds__(256) void k_merge_s(Params p, int s) {
    __shared__ __align__(16) char sm[5440];
    int pp = s & 1;
    merge_body(p, sm,
               pp ? p.cum1 : p.cum0, pp ? p.len1 : p.len0, pp ? p.fin1 : p.fin0,
               pp ? p.lat1 : p.lat0, pp ? p.tok1 : p.tok0,
               pp ? p.cum0 : p.cum1, pp ? p.len0 : p.len1, pp ? p.fin0 : p.fin1,
               pp ? p.lat0 : p.lat1, pp ? p.tok0 : p.tok1, s);
}
__global__ void k_final_s(Params p) {
    __shared__ __align__(16) char sm[16];
    final_body(p, sm);
}

extern "C" void kernel_launch(void* const* d_in, const int* in_sizes, int n_in,
                              void* d_out, int out_size, void* d_ws, size_t ws_size,
                              hipStream_t stream) {
    Params p;
    p.emb  = (const float*)d_in[0];
    p.Wx   = (const float*)d_in[1];
    p.Wh   = (const float*)d_in[2];
    p.Wout = (const float*)d_in[3];
    p.bout = (const float*)d_in[4];
    p.enc  = (const float*)d_in[5];
    p.h0   = (const float*)d_in[6];
    p.out  = (float*)d_out;

    char* w = (char*)d_ws;
    auto alloc = [&](size_t bytes) -> char* {
        char* q = w; w += (bytes + 255) & ~(size_t)255; return q;
    };

    p.h    = (float*)alloc((size_t)BS*H*4);
    p.hcT  = (float*)alloc((size_t)2*H*BS*4);
    p.part = (float*)alloc((size_t)KS*4*BS*H*4);        // 2 MiB
    p.attg = (float*)alloc((size_t)BS*S*4);
    p.cum0 = (float*)alloc(8*4);
    p.cum1 = (float*)alloc(8*4);
    p.len0 = (int*)alloc(8*4);  p.len1 = (int*)alloc(8*4);
    p.fin0 = (int*)alloc(8*4);  p.fin1 = (int*)alloc(8*4);
    p.lat0 = (int*)alloc(8*4);  p.lat1 = (int*)alloc(8*4);
    p.tok0 = (int*)alloc((size_t)BS*T*4);
    p.tok1 = (int*)alloc((size_t)BS*T*4);
    p.lpart  = (float*)alloc((size_t)8*BS*V*4);         // 12.87 MiB
    p.cand_v = (float*)alloc(8*8*8*4);
    p.cand_i = (int*)  alloc(8*8*8*4);
    p.cm     = (float*)alloc(64*4);
    p.clp    = (float*)alloc(64*4);

    // ---- cooperative persistent path ----
    bool coop = false;
    int maxb = 0;
    hipError_t oe = hipOccupancyMaxActiveBlocksPerMultiprocessor(&maxb, k_all, 256, 0);
    if (oe == hipSuccess && maxb >= 1) {
        int grid = maxb * 256;                 // 256 CUs on MI355X
        if (grid > 1024) grid = 1024;
        if (grid < 256)  grid = 256;
        void* args[] = { (void*)&p };
        hipError_t le = hipLaunchCooperativeKernel((const void*)k_all,
                                                   dim3(grid), dim3(256),
                                                   args, 0, stream);
        if (le == hipSuccess) coop = true;
    }

    if (!coop) {
        // fallback: identical bodies, multi-kernel (round-1 parity + ctx split)
        k_init_s<<<1, 256, 0, stream>>>(p);
        for (int s = 0; s < T; ++s) {
            k_gru_s <<<dim3(4, KS), 256, 0, stream>>>(p, s);
            k_gate_s<<<BS,          256, 0, stream>>>(p);
            k_ctx_s <<<32,          256, 0, stream>>>(p);
            k_gemv_s<<<dim3(CB, 8), 256, 0, stream>>>(p);
            k_topk_s<<<dim3(BS, 8), 256, 0, stream>>>(p);
            k_merge_s<<<1,          256, 0, stream>>>(p, s);
        }
        k_final_s<<<1, 64, 0, stream>>>(p);
    }
}